// Round 14
// baseline (567.762 us; speedup 1.0000x reference)
//
#include <hip/hip_runtime.h>
#include <hip/hip_bf16.h>

typedef _Float16 h2_t  __attribute__((ext_vector_type(2)));
typedef _Float16 f16x8 __attribute__((ext_vector_type(8)));
typedef float    f32x4 __attribute__((ext_vector_type(4)));

#define NLG    196608
#define DIM    256
#define NRELS  237
#define BG     128
#define NN     256
#define MM     (BG*NN)      // 32768
#define G3     768          // 3*DIM
#define NSPLIT 64
#define NBWD   8            // backward blocks (16 graphs each)
#define GPB    16

// ---------------- A0: needed-relation flags ----------------
__global__ void k_needed(const int* __restrict__ rel, int* __restrict__ needed){
  int t = threadIdx.x;
  needed[t] = 0;
  __syncthreads();
  if (t < BG) atomicOr(&needed[rel[t]], 1);
}

// ---------------- B0: X16 = f16(relu(emds+bias)), h0 = max_n(node) ----------------
__global__ __launch_bounds__(256) void k_prep(const float* __restrict__ emds,
     const float* __restrict__ gbias, _Float16* __restrict__ X16, float* __restrict__ h0){
  int b = blockIdx.x, d = threadIdx.x;
  float bi = gbias[d];
  float mx = -3.4e38f;
  const float* src = emds + (size_t)b*NN*DIM + d;
  _Float16* dst = X16 + (size_t)b*NN*DIM + d;
  #pragma unroll 4
  for (int n = 0; n < NN; ++n){
    float v = src[(size_t)n*DIM];
    mx = fmaxf(mx, v);
    dst[(size_t)n*DIM] = (_Float16)fmaxf(v + bi, 0.f);
  }
  h0[b*DIM + d] = mx;
}

// ---------------- B2: wih_b, whh_b -> f16 row-major [768][256] ----------------
__global__ __launch_bounds__(256) void k_wconv(const float* __restrict__ wih,
      const float* __restrict__ whh, _Float16* __restrict__ wih16,
      _Float16* __restrict__ whh16){
  int t = blockIdx.x*256 + threadIdx.x;      // 0..49151
  const float* src; _Float16* dst; int i;
  if (t < 24576){ src = wih; dst = wih16; i = t*8; }
  else          { src = whh; dst = whh16; i = (t-24576)*8; }
  float4 a = *(const float4*)(src + i);
  float4 b = *(const float4*)(src + i + 4);
  f16x8 v;
  v[0]=(_Float16)a.x; v[1]=(_Float16)a.y; v[2]=(_Float16)a.z; v[3]=(_Float16)a.w;
  v[4]=(_Float16)b.x; v[5]=(_Float16)b.y; v[6]=(_Float16)b.z; v[7]=(_Float16)b.w;
  *(f16x8*)(dst + i) = v;
}

// ---------------- C: gi16[t][g][768] = f16(X @ w_ih_b^T + b_ih_b + bhh_fold) ----
__global__ __launch_bounds__(256) void k_gemm_gi(const _Float16* __restrict__ X16,
        const _Float16* __restrict__ wih16, const float* __restrict__ bih,
        const float* __restrict__ bhh, _Float16* __restrict__ gi16){
  __shared__ __align__(16) _Float16 Xs[64*136];
  __shared__ __align__(16) _Float16 Ws[64*136];
  int m0 = (blockIdx.x / 12) * 64;
  int n0 = (blockIdx.x % 12) * 64;
  int tix = threadIdx.x;
  int w = tix >> 6, l = tix & 63;
  int wm = (w & 1) * 32, wn = (w >> 1) * 32;
  int fr = l & 15, kg = l >> 4;
  f32x4 acc[2][2] = {};
  for (int kh = 0; kh < 2; ++kh){
    if (kh) __syncthreads();
    for (int rnd = 0; rnd < 4; ++rnd){
      int chunk = rnd*256 + tix;
      int r = chunk >> 4, cc = chunk & 15;
      *(f16x8*)&Xs[r*136 + cc*8] = *(const f16x8*)&X16[(size_t)(m0+r)*DIM + kh*128 + cc*8];
      *(f16x8*)&Ws[r*136 + cc*8] = *(const f16x8*)&wih16[(size_t)(n0+r)*DIM + kh*128 + cc*8];
    }
    __syncthreads();
    #pragma unroll
    for (int kk = 0; kk < 4; ++kk){
      int kcol = kk*32 + kg*8;
      f16x8 a0 = *(const f16x8*)&Xs[(wm + fr)*136 + kcol];
      f16x8 a1 = *(const f16x8*)&Xs[(wm + 16 + fr)*136 + kcol];
      f16x8 b0 = *(const f16x8*)&Ws[(wn + fr)*136 + kcol];
      f16x8 b1 = *(const f16x8*)&Ws[(wn + 16 + fr)*136 + kcol];
      acc[0][0] = __builtin_amdgcn_mfma_f32_16x16x32_f16(a0,b0,acc[0][0],0,0,0);
      acc[0][1] = __builtin_amdgcn_mfma_f32_16x16x32_f16(a0,b1,acc[0][1],0,0,0);
      acc[1][0] = __builtin_amdgcn_mfma_f32_16x16x32_f16(a1,b0,acc[1][0],0,0,0);
      acc[1][1] = __builtin_amdgcn_mfma_f32_16x16x32_f16(a1,b1,acc[1][1],0,0,0);
    }
  }
  int col0 = n0 + wn + fr;
  float bv0 = bih[col0] + (col0 < 512 ? bhh[col0] : 0.f);
  float bv1 = bih[col0+16] + (col0+16 < 512 ? bhh[col0+16] : 0.f);
  __syncthreads();
  _Float16* stage = (_Float16*)Xs;
  #pragma unroll
  for (int i = 0; i < 2; ++i)
  #pragma unroll
  for (int j = 0; j < 2; ++j){
    float bv = j ? bv1 : bv0;
    #pragma unroll
    for (int v = 0; v < 4; ++v){
      int srow = wm + i*16 + kg*4 + v;
      int scol = wn + j*16 + fr;
      stage[srow*72 + scol] = (_Float16)(acc[i][j][v] + bv);
    }
  }
  __syncthreads();
  {
    int r = tix >> 2, ch = tix & 3;
    int t0 = m0 & 255, gg = m0 >> 8;
    const f16x8* src = (const f16x8*)(stage + r*72 + ch*16);
    _Float16* dst = gi16 + (size_t)(t0 + r)*(BG*G3) + (size_t)gg*G3 + n0 + ch*16;
    *(f16x8*)(dst)   = src[0];
    *(f16x8*)(dst+8) = src[1];
  }
}

// ---- helpers ----
__device__ __forceinline__ uint2 pack4(float a, float b, float c, float d){
  h2_t p0; p0[0] = (_Float16)a; p0[1] = (_Float16)b;
  h2_t p1; p1[0] = (_Float16)c; p1[1] = (_Float16)d;
  uint2 r; r.x = __builtin_bit_cast(unsigned int, p0);
  r.y = __builtin_bit_cast(unsigned int, p1);
  return r;
}
__device__ __forceinline__ f32x4 cvt4(uint2 u){
  h2_t a = __builtin_bit_cast(h2_t, u.x), b = __builtin_bit_cast(h2_t, u.y);
  f32x4 r; r[0]=(float)a[0]; r[1]=(float)a[1]; r[2]=(float)b[0]; r[3]=(float)b[1];
  return r;
}
__device__ __forceinline__ float sigf(float x){
  return __builtin_amdgcn_rcpf(1.f + __expf(-x));
}
__device__ __forceinline__ float tanhff(float x){
  float e = __expf(2.f*x);
  return 1.f - 2.f*__builtin_amdgcn_rcpf(e + 1.f);
}

// ---------------- D: mega kernel ----------------
// blocks 0..7: backward chains, 16 graphs each (zero MFMA N-waste; acc feeds
//   act directly on all 64 lanes — no redistribution). gi: per-thread 48B
//   coalesced global load (full-step cover) -> dbuf LDS stage published at
//   step START (write-early/read-late); act reads 6 contiguous ds_read_b64.
//   One lgkm-only barrier per step.
// blocks 8..135: forward GRU (2 steps). blocks 136..391: segment-sum.
__global__ __launch_bounds__(512, 2) void k_mega(
    const _Float16* __restrict__ whh16, const _Float16* __restrict__ gi16,
    const float* __restrict__ h0, const float* __restrict__ bhh,
    float* __restrict__ bwd1, float* __restrict__ bwd0,
    const float* __restrict__ emds, const float* __restrict__ gbias,
    const float* __restrict__ wihf, const float* __restrict__ whhf,
    const float* __restrict__ bihf, const float* __restrict__ bhhf,
    float* __restrict__ fwd0, float* __restrict__ fwd1,
    const float* __restrict__ lgf, const int* __restrict__ lgt,
    const int* __restrict__ needed,
    float* __restrict__ part, int* __restrict__ cntp){
  __shared__ __align__(16) char smem[66560];
  const int bid = blockIdx.x;
  const int tid = threadIdx.x;
  if (bid < NBWD){
    char* hls0 = smem;                       // 8 KB h buffer A
    char* hls1 = smem + 8192;                // 8 KB h buffer B
    float* bnl = (float*)(smem + 16384);     // 1 KB b_hh_n
    char* gstA = smem + 17408;               // 24 KB gi stage A
    char* gstB = smem + 41984;               // 24 KB gi stage B
    const int w = tid >> 6, l = tid & 63;
    const int lq = l >> 4, fr = l & 15;
    const int gg = bid*GPB + fr;             // this lane's graph
    const int dbase = w*32 + lq*4;
    const int hoff = w*1024 + (lq>>1)*256 + fr*16 + (lq&1)*8;
    const int gboff = fr*1536 + dbase*2;     // stage byte offset (gate adds 512, dt adds 32)

    if (tid < 256) bnl[tid] = bhh[512 + tid];

    // ---- all 6 weight tiles in regs: wf[gate*2+dt][kc] (192 regs) ----
    f16x8 wf[6][8];
    #pragma unroll
    for (int t6 = 0; t6 < 6; ++t6){
      const int gate = t6 >> 1, dth = t6 & 1;
      const _Float16* wr = whh16 + (size_t)(gate*256 + w*32 + dth*16 + fr)*256 + lq*8;
      #pragma unroll
      for (int kc = 0; kc < 8; ++kc)
        wf[t6][kc] = *(const f16x8*)(wr + kc*32);
    }
    // ---- h_old packed f16, hls0 init (all 16 cols real -> no zeroing) ----
    uint2 hop[2];
    #pragma unroll
    for (int dt = 0; dt < 2; ++dt){
      float4 h4 = *(const float4*)(h0 + (size_t)gg*DIM + dbase + dt*16);
      hop[dt] = pack4(h4.x, h4.y, h4.z, h4.w);
      *(uint2*)(hls0 + hoff + dt*512) = hop[dt];
    }
    // ---- gi prologue: s=0 (t=255) -> gstA; preload s=1 regs ----
    const char* gsrc = (const char*)gi16
        + ((size_t)255*BG + (size_t)bid*GPB)*(size_t)G3*2;
    {
      uint4 a = *(const uint4*)(gsrc + tid*48);
      uint4 b = *(const uint4*)(gsrc + tid*48 + 16);
      uint4 c = *(const uint4*)(gsrc + tid*48 + 32);
      *(uint4*)(gstA + tid*48)      = a;
      *(uint4*)(gstA + tid*48 + 16) = b;
      *(uint4*)(gstA + tid*48 + 32) = c;
    }
    gsrc -= (size_t)BG*G3*2;
    uint4 gih0 = *(const uint4*)(gsrc + tid*48);
    uint4 gih1 = *(const uint4*)(gsrc + tid*48 + 16);
    uint4 gih2 = *(const uint4*)(gsrc + tid*48 + 32);
    __syncthreads();

#define GRU_STEP(HR, HW, GCUR, GNXT, S)                                       \
    {                                                                         \
      /* publish gi(S+1) (loaded a full step ago) into next stage buffer */   \
      if ((S) < 255){                                                         \
        *(uint4*)((char*)(GNXT) + tid*48)      = gih0;                        \
        *(uint4*)((char*)(GNXT) + tid*48 + 16) = gih1;                        \
        *(uint4*)((char*)(GNXT) + tid*48 + 32) = gih2;                        \
      }                                                                       \
      /* issue coalesced loads for gi(S+2) */                                 \
      if ((S) < 254){                                                         \
        gsrc -= (size_t)BG*G3*2;                                              \
        gih0 = *(const uint4*)(gsrc + tid*48);                                \
        gih1 = *(const uint4*)(gsrc + tid*48 + 16);                           \
        gih2 = *(const uint4*)(gsrc + tid*48 + 32);                           \
      }                                                                       \
      f32x4 acc0 = {}, acc1 = {}, acc2 = {}, acc3 = {};                       \
      f32x4 acc4 = *(const f32x4*)(bnl + dbase);                              \
      f32x4 acc5 = *(const f32x4*)(bnl + dbase + 16);                         \
      _Pragma("unroll")                                                       \
      for (int kc = 0; kc < 8; ++kc){                                         \
        f16x8 bf = *(const f16x8*)((HR) + kc*1024 + l*16);                    \
        acc0 = __builtin_amdgcn_mfma_f32_16x16x32_f16(wf[0][kc], bf, acc0,0,0,0);\
        acc1 = __builtin_amdgcn_mfma_f32_16x16x32_f16(wf[1][kc], bf, acc1,0,0,0);\
        acc2 = __builtin_amdgcn_mfma_f32_16x16x32_f16(wf[2][kc], bf, acc2,0,0,0);\
        acc3 = __builtin_amdgcn_mfma_f32_16x16x32_f16(wf[3][kc], bf, acc3,0,0,0);\
        acc4 = __builtin_amdgcn_mfma_f32_16x16x32_f16(wf[4][kc], bf, acc4,0,0,0);\
        acc5 = __builtin_amdgcn_mfma_f32_16x16x32_f16(wf[5][kc], bf, acc5,0,0,0);\
      }                                                                       \
      _Pragma("unroll")                                                       \
      for (int dt = 0; dt < 2; ++dt){                                         \
        f32x4 gir = cvt4(*(const uint2*)((char*)(GCUR) + gboff + dt*32));     \
        f32x4 giz = cvt4(*(const uint2*)((char*)(GCUR) + gboff + 512 + dt*32));\
        f32x4 gin = cvt4(*(const uint2*)((char*)(GCUR) + gboff + 1024 + dt*32));\
        f32x4 hov = cvt4(hop[dt]);                                            \
        f32x4 ar = dt ? acc1 : acc0;                                          \
        f32x4 az = dt ? acc3 : acc2;                                          \
        f32x4 an = dt ? acc5 : acc4;                                          \
        float h_[4];                                                          \
        _Pragma("unroll")                                                     \
        for (int v = 0; v < 4; ++v){                                          \
          float r  = sigf(gir[v] + ar[v]);                                    \
          float z  = sigf(giz[v] + az[v]);                                    \
          float nn = tanhff(gin[v] + r*an[v]);                                \
          h_[v] = z*(hov[v] - nn) + nn;                                       \
        }                                                                     \
        hop[dt] = pack4(h_[0], h_[1], h_[2], h_[3]);                          \
        *(uint2*)((HW) + hoff + dt*512) = hop[dt];                            \
        if ((S) == 254)                                                       \
          *(float4*)(bwd1 + (size_t)gg*DIM + dbase + dt*16)                   \
              = make_float4(h_[0], h_[1], h_[2], h_[3]);                      \
        if ((S) == 255)                                                       \
          *(float4*)(bwd0 + (size_t)gg*DIM + dbase + dt*16)                   \
              = make_float4(h_[0], h_[1], h_[2], h_[3]);                      \
      }                                                                       \
      asm volatile("s_waitcnt lgkmcnt(0)" ::: "memory");                      \
      __builtin_amdgcn_s_barrier();                                           \
    }

    for (int s2 = 0; s2 < 128; ++s2){
      GRU_STEP(hls0, hls1, gstA, gstB, 2*s2);
      GRU_STEP(hls1, hls0, gstB, gstA, 2*s2 + 1);
    }
#undef GRU_STEP
  } else if (bid < NBWD + BG){
    // ---- forward GRU: fwd[0], fwd[1] only ----
    const int b = bid - NBWD;
    float* xv0  = (float*)smem;
    float* xv1  = (float*)(smem + 1024);
    float* hc   = (float*)(smem + 2048);
    float* frz2 = (float*)(smem + 3072);
    float* fhn2 = (float*)(smem + 5120);
    float* fin2 = (float*)(smem + 6144);
    const int j = threadIdx.x;
    if (j < 256){
      float bi = gbias[j];
      xv0[j] = fmaxf(emds[(size_t)b*NN*DIM + j] + bi, 0.f);
      xv1[j] = fmaxf(emds[(size_t)b*NN*DIM + DIM + j] + bi, 0.f);
      hc[j] = h0[(size_t)b*DIM + j];
    }
    __syncthreads();
    for (int st = 0; st < 2; ++st){
      const float* xv = st ? xv1 : xv0;
      const float4* wi = (const float4*)(wihf + (size_t)j*DIM);
      const float4* wh = (const float4*)(whhf + (size_t)j*DIM);
      const int row2 = 256 + j;
      const float4* wi2 = (const float4*)(wihf + (size_t)row2*DIM);
      const float4* wh2 = (const float4*)(whhf + (size_t)row2*DIM);
      float g1 = bihf[j] + bhhf[j];
      float gi2 = 0.f, gh2 = 0.f;
      if (j >= 256){ gi2 = bihf[row2]; gh2 = bhhf[row2]; }
      #pragma unroll 4
      for (int c = 0; c < 64; ++c){
        float4 x4 = *(const float4*)&xv[c*4];
        float4 h4 = *(const float4*)&hc[c*4];
        float4 a = wi[c], hh = wh[c];
        g1 += a.x*x4.x + a.y*x4.y + a.z*x4.z + a.w*x4.w;
        g1 += hh.x*h4.x + hh.y*h4.y + hh.z*h4.z + hh.w*h4.w;
        if (j >= 256){
          float4 a2 = wi2[c], hh2 = wh2[c];
          gi2 += a2.x*x4.x + a2.y*x4.y + a2.z*x4.z + a2.w*x4.w;
          gh2 += hh2.x*h4.x + hh2.y*h4.y + hh2.z*h4.z + hh2.w*h4.w;
        }
      }
      frz2[j] = g1;
      if (j >= 256){ fin2[j-256] = gi2; fhn2[j-256] = gh2; }
      __syncthreads();
      if (j < 256){
        float r = sigf(frz2[j]);
        float z = sigf(frz2[256+j]);
        float n = tanhff(fin2[j] + r*fhn2[j]);
        float hnew = z*(hc[j] - n) + n;
        hc[j] = hnew;
        if (st == 0) fwd0[(size_t)b*DIM + j] = hnew;
        else         fwd1[(size_t)b*DIM + j] = hnew;
      }
      __syncthreads();
    }
  } else {
    // ---- segment-sum partials: 64 splits x 4 dim-chunks, 512 threads ----
    const int idx = bid - (NBWD + BG);
    const int split = idx >> 2, chunk = idx & 3;
    const int c0 = chunk * 64;
    float* acc  = (float*)smem;                 // NRELS*64*4 = 60672
    int*   cacc = (int*)(smem + 60672);
    int*   sneed= (int*)(smem + 61632);
    const int t = threadIdx.x, lane = t & 63, wv = t >> 6;
    for (int i = t; i < NRELS*64; i += 512) acc[i] = 0.f;
    for (int i = t; i < NRELS; i += 512){ cacc[i] = 0; sneed[i] = needed[i]; }
    __syncthreads();
    const int RPS = NLG / NSPLIT;               // 3072
    const int rbase = split * RPS;
    for (int it = 0; it < RPS/16; ++it){
      int r0 = rbase + it*16 + wv*2;
      int ty0 = lgt[r0], ty1 = lgt[r0+1];
      int nd0 = sneed[ty0], nd1 = sneed[ty1];
      float v0 = 0.f, v1 = 0.f;
      if (nd0) v0 = lgf[(size_t)r0*DIM + c0 + lane];
      if (nd1) v1 = lgf[(size_t)(r0+1)*DIM + c0 + lane];
      if (nd0){ atomicAdd(&acc[ty0*64 + lane], v0);
                if (chunk==0 && lane==0) atomicAdd(&cacc[ty0], 1); }
      if (nd1){ atomicAdd(&acc[ty1*64 + lane], v1);
                if (chunk==0 && lane==0) atomicAdd(&cacc[ty1], 1); }
    }
    __syncthreads();
    for (int i = t; i < NRELS*64; i += 512){
      int r = i >> 6, dd = i & 63;
      part[((size_t)split*NRELS + r)*DIM + c0 + dd] = acc[i];
    }
    if (chunk==0) for (int i = t; i < NRELS; i += 512) cntp[split*NRELS + i] = cacc[i];
  }
}

// ---------------- E: head (computes its own relation mean from partials) ----
__global__ __launch_bounds__(256) void k_head(const float* __restrict__ fwd0,
     const float* __restrict__ fwd1, const float* __restrict__ bwd1,
     const float* __restrict__ bwd0,
     const float* __restrict__ part, const int* __restrict__ cntp,
     const int* __restrict__ rel,
     const float* __restrict__ W3, const float* __restrict__ b3,
     const float* __restrict__ W1, const float* __restrict__ b1,
     const float* __restrict__ W2, const float* __restrict__ b2,
     float* __restrict__ out){
  int b = blockIdx.x, d = threadIdx.x;
  __shared__ float cat0[512], cat1[512], feat[256];
  cat0[d] = fwd0[b*DIM+d]; cat0[256+d] = bwd0[b*DIM+d];
  cat1[d] = fwd1[b*DIM+d]; cat1[256+d] = bwd1[b*DIM+d];
  int lab = rel[b];
  float ps = 0.f;
  #pragma unroll 4
  for (int sp = 0; sp < NSPLIT; ++sp)
    ps += part[((size_t)sp*NRELS + lab)*DIM + d];
  int cs = 0;
  for (int sp = 0; sp < NSPLIT; ++sp) cs += cntp[sp*NRELS + lab];
  float mv = (cs > 0) ? ps / (float)cs : 0.f;
  __syncthreads();
  const float4* w3r = (const float4*)(W3 + (size_t)d*512);
  float hd = b3[d], td = b3[d];
  #pragma unroll 8
  for (int c = 0; c < 128; ++c){
    float4 w = w3r[c];
    hd += w.x*cat0[c*4] + w.y*cat0[c*4+1] + w.z*cat0[c*4+2] + w.w*cat0[c*4+3];
    td += w.x*cat1[c*4] + w.y*cat1[c*4+1] + w.z*cat1[c*4+2] + w.w*cat1[c*4+3];
  }
  feat[d] = fmaxf(hd, 0.f) + mv - fmaxf(td, 0.f);
  __syncthreads();
  const float4* w1r = (const float4*)(W1 + (size_t)d*DIM);
  float s = b1[d];
  #pragma unroll 8
  for (int c = 0; c < 64; ++c){
    float4 w = w1r[c];
    s += w.x*feat[c*4] + w.y*feat[c*4+1] + w.z*feat[c*4+2] + w.w*feat[c*4+3];
  }
  float v = W2[d] * s;
  #pragma unroll
  for (int o = 32; o > 0; o >>= 1) v += __shfl_down(v, o, 64);
  __shared__ float red[4];
  if ((d & 63) == 0) red[d >> 6] = v;
  __syncthreads();
  if (d == 0) out[b] = red[0] + red[1] + red[2] + red[3] + b2[0];
}

extern "C" void kernel_launch(void* const* d_in, const int* in_sizes, int n_in,
                              void* d_out, int out_size, void* d_ws, size_t ws_size,
                              hipStream_t stream){
  const float* lg_feats = (const float*)d_in[0];
  const int*   lg_type  = (const int*)d_in[1];
  const float* emds     = (const float*)d_in[2];
  const int*   rel      = (const int*)d_in[3];
  const float* gbias    = (const float*)d_in[4];
  const float* wihf     = (const float*)d_in[5];
  const float* whhf     = (const float*)d_in[6];
  const float* bihf     = (const float*)d_in[7];
  const float* bhhf     = (const float*)d_in[8];
  const float* wihb     = (const float*)d_in[9];
  const float* whhb     = (const float*)d_in[10];
  const float* bihb     = (const float*)d_in[11];
  const float* bhhb     = (const float*)d_in[12];
  const float* W3 = (const float*)d_in[13];
  const float* b3 = (const float*)d_in[14];
  const float* W1 = (const float*)d_in[15];
  const float* b1 = (const float*)d_in[16];
  const float* W2 = (const float*)d_in[17];
  const float* b2 = (const float*)d_in[18];
  float* out = (float*)d_out;

  char* ws = (char*)d_ws;
  size_t off = 0;
  auto alloc = [&](size_t bytes){ size_t o = off; off += (bytes + 255) & ~(size_t)255; return o; };
  size_t o_needed = alloc(256*4);
  size_t o_cntp   = alloc((size_t)NSPLIT*NRELS*4);
  size_t o_h0     = alloc((size_t)BG*DIM*4);
  size_t o_X16    = alloc((size_t)MM*DIM*2);
  size_t o_wih16  = alloc((size_t)G3*DIM*2);
  size_t o_whh16  = alloc((size_t)G3*DIM*2);
  size_t o_f0     = alloc((size_t)BG*DIM*4);
  size_t o_f1     = alloc((size_t)BG*DIM*4);
  size_t o_b1v    = alloc((size_t)BG*DIM*4);
  size_t o_b0v    = alloc((size_t)BG*DIM*4);
  size_t o_part   = alloc((size_t)NSPLIT*NRELS*DIM*4);
  size_t o_gi     = alloc((size_t)MM*G3*2);
  (void)ws_size; (void)in_sizes; (void)n_in; (void)out_size;

  int*       needed = (int*)(ws + o_needed);
  int*       cntp   = (int*)(ws + o_cntp);
  float*     h0     = (float*)(ws + o_h0);
  _Float16*  X16    = (_Float16*)(ws + o_X16);
  _Float16*  wih16  = (_Float16*)(ws + o_wih16);
  _Float16*  whh16  = (_Float16*)(ws + o_whh16);
  float*     f0     = (float*)(ws + o_f0);
  float*     f1     = (float*)(ws + o_f1);
  float*     b1v    = (float*)(ws + o_b1v);
  float*     b0v    = (float*)(ws + o_b0v);
  float*     part   = (float*)(ws + o_part);
  _Float16*  gi16   = (_Float16*)(ws + o_gi);

  k_needed<<<1, 256, 0, stream>>>(rel, needed);
  k_prep  <<<BG, 256, 0, stream>>>(emds, gbias, X16, h0);
  k_wconv <<<192, 256, 0, stream>>>(wihb, whhb, wih16, whh16);
  k_gemm_gi<<<(MM/64)*(G3/64), 256, 0, stream>>>(X16, wih16, bihb, bhhb, gi16);
  k_mega  <<<NBWD + BG + NSPLIT*4, 512, 0, stream>>>(whh16, gi16, h0, bhhb, b1v, b0v,
                                       emds, gbias, wihf, whhf, bihf, bhhf, f0, f1,
                                       lg_feats, lg_type, needed, part, cntp);
  k_head  <<<BG, 256, 0, stream>>>(f0, f1, b1v, b0v, part, cntp, rel,
                                   W3, b3, W1, b1, W2, b2, out);
}

// Round 15
// 402.739 us; speedup vs baseline: 1.4098x; 1.4098x over previous
//
#include <hip/hip_runtime.h>
#include <hip/hip_bf16.h>

typedef _Float16 h2_t  __attribute__((ext_vector_type(2)));
typedef _Float16 f16x8 __attribute__((ext_vector_type(8)));
typedef float    f32x4 __attribute__((ext_vector_type(4)));

#define NLG    196608
#define DIM    256
#define NRELS  237
#define BG     128
#define NN     256
#define MM     (BG*NN)      // 32768
#define G3     768          // 3*DIM
#define NSPLIT 64
#define NBWD   64           // backward blocks (2 graphs each)

// ---------------- P: fused prologue ----------------
// block 0: needed flags; blocks 1..128: prep (X16, h0); blocks 129..320: wconv
__global__ __launch_bounds__(256) void k_pre(const int* __restrict__ rel,
     int* __restrict__ needed,
     const float* __restrict__ emds, const float* __restrict__ gbias,
     _Float16* __restrict__ X16, float* __restrict__ h0,
     const float* __restrict__ wih, const float* __restrict__ whh,
     _Float16* __restrict__ wih16, _Float16* __restrict__ whh16){
  const int bid = blockIdx.x;
  const int tid = threadIdx.x;
  if (bid == 0){
    needed[tid] = 0;
    __syncthreads();
    if (tid < BG) atomicOr(&needed[rel[tid]], 1);
  } else if (bid <= BG){
    const int b = bid - 1, d = tid;
    float bi = gbias[d];
    float mx = -3.4e38f;
    const float* src = emds + (size_t)b*NN*DIM + d;
    _Float16* dst = X16 + (size_t)b*NN*DIM + d;
    #pragma unroll 4
    for (int n = 0; n < NN; ++n){
      float v = src[(size_t)n*DIM];
      mx = fmaxf(mx, v);
      dst[(size_t)n*DIM] = (_Float16)fmaxf(v + bi, 0.f);
    }
    h0[b*DIM + d] = mx;
  } else {
    int t = (bid - (BG+1))*256 + tid;        // 0..49151
    const float* src; _Float16* dst; int i;
    if (t < 24576){ src = wih; dst = wih16; i = t*8; }
    else          { src = whh; dst = whh16; i = (t-24576)*8; }
    float4 a = *(const float4*)(src + i);
    float4 b = *(const float4*)(src + i + 4);
    f16x8 v;
    v[0]=(_Float16)a.x; v[1]=(_Float16)a.y; v[2]=(_Float16)a.z; v[3]=(_Float16)a.w;
    v[4]=(_Float16)b.x; v[5]=(_Float16)b.y; v[6]=(_Float16)b.z; v[7]=(_Float16)b.w;
    *(f16x8*)(dst + i) = v;
  }
}

// ---------------- C: gi16[t][g][768] = f16(X @ w_ih_b^T + b_ih_b + bhh_fold) ----
__global__ __launch_bounds__(256) void k_gemm_gi(const _Float16* __restrict__ X16,
        const _Float16* __restrict__ wih16, const float* __restrict__ bih,
        const float* __restrict__ bhh, _Float16* __restrict__ gi16){
  __shared__ __align__(16) _Float16 Xs[64*136];
  __shared__ __align__(16) _Float16 Ws[64*136];
  int m0 = (blockIdx.x / 12) * 64;
  int n0 = (blockIdx.x % 12) * 64;
  int tix = threadIdx.x;
  int w = tix >> 6, l = tix & 63;
  int wm = (w & 1) * 32, wn = (w >> 1) * 32;
  int fr = l & 15, kg = l >> 4;
  f32x4 acc[2][2] = {};
  for (int kh = 0; kh < 2; ++kh){
    if (kh) __syncthreads();
    for (int rnd = 0; rnd < 4; ++rnd){
      int chunk = rnd*256 + tix;
      int r = chunk >> 4, cc = chunk & 15;
      *(f16x8*)&Xs[r*136 + cc*8] = *(const f16x8*)&X16[(size_t)(m0+r)*DIM + kh*128 + cc*8];
      *(f16x8*)&Ws[r*136 + cc*8] = *(const f16x8*)&wih16[(size_t)(n0+r)*DIM + kh*128 + cc*8];
    }
    __syncthreads();
    #pragma unroll
    for (int kk = 0; kk < 4; ++kk){
      int kcol = kk*32 + kg*8;
      f16x8 a0 = *(const f16x8*)&Xs[(wm + fr)*136 + kcol];
      f16x8 a1 = *(const f16x8*)&Xs[(wm + 16 + fr)*136 + kcol];
      f16x8 b0 = *(const f16x8*)&Ws[(wn + fr)*136 + kcol];
      f16x8 b1 = *(const f16x8*)&Ws[(wn + 16 + fr)*136 + kcol];
      acc[0][0] = __builtin_amdgcn_mfma_f32_16x16x32_f16(a0,b0,acc[0][0],0,0,0);
      acc[0][1] = __builtin_amdgcn_mfma_f32_16x16x32_f16(a0,b1,acc[0][1],0,0,0);
      acc[1][0] = __builtin_amdgcn_mfma_f32_16x16x32_f16(a1,b0,acc[1][0],0,0,0);
      acc[1][1] = __builtin_amdgcn_mfma_f32_16x16x32_f16(a1,b1,acc[1][1],0,0,0);
    }
  }
  int col0 = n0 + wn + fr;
  float bv0 = bih[col0] + (col0 < 512 ? bhh[col0] : 0.f);
  float bv1 = bih[col0+16] + (col0+16 < 512 ? bhh[col0+16] : 0.f);
  __syncthreads();
  _Float16* stage = (_Float16*)Xs;
  #pragma unroll
  for (int i = 0; i < 2; ++i)
  #pragma unroll
  for (int j = 0; j < 2; ++j){
    float bv = j ? bv1 : bv0;
    #pragma unroll
    for (int v = 0; v < 4; ++v){
      int srow = wm + i*16 + kg*4 + v;
      int scol = wn + j*16 + fr;
      stage[srow*72 + scol] = (_Float16)(acc[i][j][v] + bv);
    }
  }
  __syncthreads();
  {
    int r = tix >> 2, ch = tix & 3;
    int t0 = m0 & 255, gg = m0 >> 8;
    const f16x8* src = (const f16x8*)(stage + r*72 + ch*16);
    _Float16* dst = gi16 + (size_t)(t0 + r)*(BG*G3) + (size_t)gg*G3 + n0 + ch*16;
    *(f16x8*)(dst)   = src[0];
    *(f16x8*)(dst+8) = src[1];
  }
}

// ---- helpers ----
__device__ __forceinline__ float sigf(float x){
  return __builtin_amdgcn_rcpf(1.f + __expf(-x));
}
__device__ __forceinline__ float tanhff(float x){
  float e = __expf(2.f*x);
  return 1.f - 2.f*__builtin_amdgcn_rcpf(e + 1.f);
}
// swizzle lane -> lane & 0b10001 (keep graph bit + 32-group bit)
__device__ __forceinline__ float swz(float x){
  return __builtin_bit_cast(float,
      __builtin_amdgcn_ds_swizzle(__builtin_bit_cast(int, x), 0x11));
}
// select component v (bools vb0 = v&1, vb1 = v&2)
__device__ __forceinline__ float sel4(f32x4 s, bool vb0, bool vb1){
  float t01 = vb0 ? s[1] : s[0];
  float t23 = vb0 ? s[3] : s[2];
  return vb1 ? t23 : t01;
}

// ---------------- D: mega kernel (round-10 known-best config) ----------------
// blocks 0..63: backward chains, 2 graphs each. All 6 W tiles in regs;
//   gi staged through LDS with coalesced 8B loads (dbuf, 1 step ahead);
//   ds_swizzle redistributes gate values so every lane activates 1 element.
// blocks 64..191: forward GRU (2 steps).
// blocks 192..447: segment-sum partials.
__global__ __launch_bounds__(512, 2) void k_mega(
    const _Float16* __restrict__ whh16, const _Float16* __restrict__ gi16,
    const float* __restrict__ h0, const float* __restrict__ bhh,
    float* __restrict__ bwd1, float* __restrict__ bwd0,
    const float* __restrict__ emds, const float* __restrict__ gbias,
    const float* __restrict__ wihf, const float* __restrict__ whhf,
    const float* __restrict__ bihf, const float* __restrict__ bhhf,
    float* __restrict__ fwd0, float* __restrict__ fwd1,
    const float* __restrict__ lgf, const int* __restrict__ lgt,
    const int* __restrict__ needed,
    float* __restrict__ part, int* __restrict__ cntp){
  __shared__ __align__(16) char smem[63488];
  const int bid = blockIdx.x;
  if (bid < NBWD){
    char* hls0 = smem;                         // 8 KB h buffer A
    char* hls1 = smem + 8192;                  // 8 KB h buffer B
    float* bnl = (float*)(smem + 16384);       // 1 KB b_hh_n
    _Float16* gst0 = (_Float16*)(smem + 17408); // 3 KB gi stage A
    _Float16* gst1 = (_Float16*)(smem + 20480); // 3 KB gi stage B
    const int tid = threadIdx.x;
    const int w = tid >> 6, l = tid & 63;
    const int lq = l >> 4, fr = l & 15;
    const int gq = fr & 1;                  // graph within block
    const int dt = (fr >> 3) & 1;           // row-half
    const int v  = (fr >> 1) & 3;           // component
    const int gg = bid*2 + gq;
    const int d  = w*32 + dt*16 + lq*4 + v; // this lane's h dim
    const int dbase0 = w*32 + lq*4;         // acc bias row base (dt=0)
    const int hslot = ((d>>3)<<8) + (gq<<4) + ((d&7)<<1);
    const int goff = gq*G3 + d;             // gi stage read offset (f16 idx)
    const bool vb0 = (v & 1), vb1 = (v & 2), dtb = dt;

    // zero both h buffers (16 KB) so cols 2..15 stay 0 forever
    for (int i = tid; i < 4096; i += 512) ((unsigned int*)smem)[i] = 0u;
    if (tid < 256) bnl[tid] = bhh[512 + tid];
    __syncthreads();

    // ---- all 6 weight tiles in regs: wf[gate*2+dt][kc] (192 regs) ----
    f16x8 wf[6][8];
    #pragma unroll
    for (int t6 = 0; t6 < 6; ++t6){
      const int gate = t6 >> 1, dth = t6 & 1;
      const _Float16* wr = whh16 + (size_t)(gate*256 + w*32 + dth*16 + fr)*256 + lq*8;
      #pragma unroll
      for (int kc = 0; kc < 8; ++kc)
        wf[t6][kc] = *(const f16x8*)(wr + kc*32);
    }
    // ---- h_old (1 f32), write f16 into hls0 ----
    float hov = h0[(size_t)gg*DIM + d];
    *(_Float16*)(hls0 + hslot) = (_Float16)hov;
    // ---- gi stage prologue: t=255 chunk (2 graphs x 768 f16 = 3072 B) ----
    const char* gsrc = (const char*)gi16 + ((size_t)255*BG + (size_t)bid*2)*(size_t)G3*2;
    if (tid < 384){
      uint2 t0v = *(const uint2*)(gsrc + tid*8);
      *(uint2*)((char*)gst0 + tid*8) = t0v;
    }
    __syncthreads();

#define GRU_STEP(HR, HW, GR, GW, S)                                           \
    {                                                                         \
      uint2 greg;                                                             \
      if ((S) < 255){                                                         \
        gsrc -= (size_t)BG*G3*2;                                              \
        if (tid < 384) greg = *(const uint2*)(gsrc + tid*8);                  \
      }                                                                       \
      float gr  = (float)((const _Float16*)(GR))[goff];                       \
      float gz  = (float)((const _Float16*)(GR))[goff+256];                   \
      float gnv = (float)((const _Float16*)(GR))[goff+512];                   \
      f32x4 acc0 = {}, acc1 = {}, acc2 = {}, acc3 = {};                       \
      f32x4 acc4 = *(const f32x4*)(bnl + dbase0);                             \
      f32x4 acc5 = *(const f32x4*)(bnl + dbase0 + 16);                        \
      _Pragma("unroll")                                                       \
      for (int kc = 0; kc < 8; ++kc){                                         \
        f16x8 bf = *(const f16x8*)((HR) + kc*1024 + l*16);                    \
        acc0 = __builtin_amdgcn_mfma_f32_16x16x32_f16(wf[0][kc], bf, acc0,0,0,0);\
        acc1 = __builtin_amdgcn_mfma_f32_16x16x32_f16(wf[1][kc], bf, acc1,0,0,0);\
        acc2 = __builtin_amdgcn_mfma_f32_16x16x32_f16(wf[2][kc], bf, acc2,0,0,0);\
        acc3 = __builtin_amdgcn_mfma_f32_16x16x32_f16(wf[3][kc], bf, acc3,0,0,0);\
        acc4 = __builtin_amdgcn_mfma_f32_16x16x32_f16(wf[4][kc], bf, acc4,0,0,0);\
        acc5 = __builtin_amdgcn_mfma_f32_16x16x32_f16(wf[5][kc], bf, acc5,0,0,0);\
      }                                                                       \
      /* redistribute gate values: src lane = (l & 0x11) */                   \
      f32x4 s0, s1;                                                           \
      s0[0]=swz(acc0[0]); s0[1]=swz(acc0[1]); s0[2]=swz(acc0[2]); s0[3]=swz(acc0[3]);\
      s1[0]=swz(acc1[0]); s1[1]=swz(acc1[1]); s1[2]=swz(acc1[2]); s1[3]=swz(acc1[3]);\
      float ar = dtb ? sel4(s1, vb0, vb1) : sel4(s0, vb0, vb1);               \
      s0[0]=swz(acc2[0]); s0[1]=swz(acc2[1]); s0[2]=swz(acc2[2]); s0[3]=swz(acc2[3]);\
      s1[0]=swz(acc3[0]); s1[1]=swz(acc3[1]); s1[2]=swz(acc3[2]); s1[3]=swz(acc3[3]);\
      float az = dtb ? sel4(s1, vb0, vb1) : sel4(s0, vb0, vb1);               \
      s0[0]=swz(acc4[0]); s0[1]=swz(acc4[1]); s0[2]=swz(acc4[2]); s0[3]=swz(acc4[3]);\
      s1[0]=swz(acc5[0]); s1[1]=swz(acc5[1]); s1[2]=swz(acc5[2]); s1[3]=swz(acc5[3]);\
      float an = dtb ? sel4(s1, vb0, vb1) : sel4(s0, vb0, vb1);               \
      float r  = sigf(gr + ar);                                               \
      float z  = sigf(gz + az);                                               \
      float nn = tanhff(gnv + r*an);                                          \
      float h  = z*(hov - nn) + nn;                                           \
      hov = h;                                                                \
      *(_Float16*)((HW) + hslot) = (_Float16)h;                               \
      if ((S) == 254) bwd1[(size_t)gg*DIM + d] = h;                           \
      if ((S) == 255) bwd0[(size_t)gg*DIM + d] = h;                           \
      if ((S) < 255 && tid < 384)                                             \
        *(uint2*)((char*)(GW) + tid*8) = greg;                                \
      asm volatile("s_waitcnt lgkmcnt(0)" ::: "memory");                      \
      __builtin_amdgcn_s_barrier();                                           \
    }

    for (int s2 = 0; s2 < 128; ++s2){
      GRU_STEP(hls0, hls1, gst0, gst1, 2*s2);
      GRU_STEP(hls1, hls0, gst1, gst0, 2*s2 + 1);
    }
#undef GRU_STEP
  } else if (bid < NBWD + BG){
    // ---- forward GRU: fwd[0], fwd[1] only ----
    const int b = bid - NBWD;
    float* xv0  = (float*)smem;
    float* xv1  = (float*)(smem + 1024);
    float* hc   = (float*)(smem + 2048);
    float* frz2 = (float*)(smem + 3072);
    float* fhn2 = (float*)(smem + 5120);
    float* fin2 = (float*)(smem + 6144);
    const int j = threadIdx.x;
    if (j < 256){
      float bi = gbias[j];
      xv0[j] = fmaxf(emds[(size_t)b*NN*DIM + j] + bi, 0.f);
      xv1[j] = fmaxf(emds[(size_t)b*NN*DIM + DIM + j] + bi, 0.f);
      hc[j] = h0[(size_t)b*DIM + j];
    }
    __syncthreads();
    for (int st = 0; st < 2; ++st){
      const float* xv = st ? xv1 : xv0;
      const float4* wi = (const float4*)(wihf + (size_t)j*DIM);
      const float4* wh = (const float4*)(whhf + (size_t)j*DIM);
      const int row2 = 256 + j;
      const float4* wi2 = (const float4*)(wihf + (size_t)row2*DIM);
      const float4* wh2 = (const float4*)(whhf + (size_t)row2*DIM);
      float g1 = bihf[j] + bhhf[j];
      float gi2 = 0.f, gh2 = 0.f;
      if (j >= 256){ gi2 = bihf[row2]; gh2 = bhhf[row2]; }
      #pragma unroll 4
      for (int c = 0; c < 64; ++c){
        float4 x4 = *(const float4*)&xv[c*4];
        float4 h4 = *(const float4*)&hc[c*4];
        float4 a = wi[c], hh = wh[c];
        g1 += a.x*x4.x + a.y*x4.y + a.z*x4.z + a.w*x4.w;
        g1 += hh.x*h4.x + hh.y*h4.y + hh.z*h4.z + hh.w*h4.w;
        if (j >= 256){
          float4 a2 = wi2[c], hh2 = wh2[c];
          gi2 += a2.x*x4.x + a2.y*x4.y + a2.z*x4.z + a2.w*x4.w;
          gh2 += hh2.x*h4.x + hh2.y*h4.y + hh2.z*h4.z + hh2.w*h4.w;
        }
      }
      frz2[j] = g1;
      if (j >= 256){ fin2[j-256] = gi2; fhn2[j-256] = gh2; }
      __syncthreads();
      if (j < 256){
        float r = sigf(frz2[j]);
        float z = sigf(frz2[256+j]);
        float n = tanhff(fin2[j] + r*fhn2[j]);
        float hnew = z*(hc[j] - n) + n;
        hc[j] = hnew;
        if (st == 0) fwd0[(size_t)b*DIM + j] = hnew;
        else         fwd1[(size_t)b*DIM + j] = hnew;
      }
      __syncthreads();
    }
  } else {
    // ---- segment-sum partials: 64 splits x 4 dim-chunks, 512 threads ----
    const int idx = bid - (NBWD + BG);
    const int split = idx >> 2, chunk = idx & 3;
    const int c0 = chunk * 64;
    float* acc  = (float*)smem;                 // NRELS*64*4 = 60672
    int*   cacc = (int*)(smem + 60672);
    int*   sneed= (int*)(smem + 61632);
    const int t = threadIdx.x, lane = t & 63, wv = t >> 6;
    for (int i = t; i < NRELS*64; i += 512) acc[i] = 0.f;
    for (int i = t; i < NRELS; i += 512){ cacc[i] = 0; sneed[i] = needed[i]; }
    __syncthreads();
    const int RPS = NLG / NSPLIT;               // 3072
    const int rbase = split * RPS;
    for (int it = 0; it < RPS/16; ++it){
      int r0 = rbase + it*16 + wv*2;
      int ty0 = lgt[r0], ty1 = lgt[r0+1];
      int nd0 = sneed[ty0], nd1 = sneed[ty1];
      float v0 = 0.f, v1 = 0.f;
      if (nd0) v0 = lgf[(size_t)r0*DIM + c0 + lane];
      if (nd1) v1 = lgf[(size_t)(r0+1)*DIM + c0 + lane];
      if (nd0){ atomicAdd(&acc[ty0*64 + lane], v0);
                if (chunk==0 && lane==0) atomicAdd(&cacc[ty0], 1); }
      if (nd1){ atomicAdd(&acc[ty1*64 + lane], v1);
                if (chunk==0 && lane==0) atomicAdd(&cacc[ty1], 1); }
    }
    __syncthreads();
    for (int i = t; i < NRELS*64; i += 512){
      int r = i >> 6, dd = i & 63;
      part[((size_t)split*NRELS + r)*DIM + c0 + dd] = acc[i];
    }
    if (chunk==0) for (int i = t; i < NRELS; i += 512) cntp[split*NRELS + i] = cacc[i];
  }
}

// ---------------- E: head (computes its own relation mean from partials) ----
__global__ __launch_bounds__(256) void k_head(const float* __restrict__ fwd0,
     const float* __restrict__ fwd1, const float* __restrict__ bwd1,
     const float* __restrict__ bwd0,
     const float* __restrict__ part, const int* __restrict__ cntp,
     const int* __restrict__ rel,
     const float* __restrict__ W3, const float* __restrict__ b3,
     const float* __restrict__ W1, const float* __restrict__ b1,
     const float* __restrict__ W2, const float* __restrict__ b2,
     float* __restrict__ out){
  int b = blockIdx.x, d = threadIdx.x;
  __shared__ float cat0[512], cat1[512], feat[256];
  cat0[d] = fwd0[b*DIM+d]; cat0[256+d] = bwd0[b*DIM+d];
  cat1[d] = fwd1[b*DIM+d]; cat1[256+d] = bwd1[b*DIM+d];
  int lab = rel[b];
  float ps = 0.f;
  #pragma unroll 4
  for (int sp = 0; sp < NSPLIT; ++sp)
    ps += part[((size_t)sp*NRELS + lab)*DIM + d];
  int cs = 0;
  for (int sp = 0; sp < NSPLIT; ++sp) cs += cntp[sp*NRELS + lab];
  float mv = (cs > 0) ? ps / (float)cs : 0.f;
  __syncthreads();
  const float4* w3r = (const float4*)(W3 + (size_t)d*512);
  float hd = b3[d], td = b3[d];
  #pragma unroll 8
  for (int c = 0; c < 128; ++c){
    float4 w = w3r[c];
    hd += w.x*cat0[c*4] + w.y*cat0[c*4+1] + w.z*cat0[c*4+2] + w.w*cat0[c*4+3];
    td += w.x*cat1[c*4] + w.y*cat1[c*4+1] + w.z*cat1[c*4+2] + w.w*cat1[c*4+3];
  }
  feat[d] = fmaxf(hd, 0.f) + mv - fmaxf(td, 0.f);
  __syncthreads();
  const float4* w1r = (const float4*)(W1 + (size_t)d*DIM);
  float s = b1[d];
  #pragma unroll 8
  for (int c = 0; c < 64; ++c){
    float4 w = w1r[c];
    s += w.x*feat[c*4] + w.y*feat[c*4+1] + w.z*feat[c*4+2] + w.w*feat[c*4+3];
  }
  float v = W2[d] * s;
  #pragma unroll
  for (int o = 32; o > 0; o >>= 1) v += __shfl_down(v, o, 64);
  __shared__ float red[4];
  if ((d & 63) == 0) red[d >> 6] = v;
  __syncthreads();
  if (d == 0) out[b] = red[0] + red[1] + red[2] + red[3] + b2[0];
}

extern "C" void kernel_launch(void* const* d_in, const int* in_sizes, int n_in,
                              void* d_out, int out_size, void* d_ws, size_t ws_size,
                              hipStream_t stream){
  const float* lg_feats = (const float*)d_in[0];
  const int*   lg_type  = (const int*)d_in[1];
  const float* emds     = (const float*)d_in[2];
  const int*   rel      = (const int*)d_in[3];
  const float* gbias    = (const float*)d_in[4];
  const float* wihf     = (const float*)d_in[5];
  const float* whhf     = (const float*)d_in[6];
  const float* bihf     = (const float*)d_in[7];
  const float* bhhf     = (const float*)d_in[8];
  const float* wihb     = (const float*)d_in[9];
  const float* whhb     = (const float*)d_in[10];
  const float* bihb     = (const float*)d_in[11];
  const float* bhhb     = (const float*)d_in[12];
  const float* W3 = (const float*)d_in[13];
  const float* b3 = (const float*)d_in[14];
  const float* W1 = (const float*)d_in[15];
  const float* b1 = (const float*)d_in[16];
  const float* W2 = (const float*)d_in[17];
  const float* b2 = (const float*)d_in[18];
  float* out = (float*)d_out;

  char* ws = (char*)d_ws;
  size_t off = 0;
  auto alloc = [&](size_t bytes){ size_t o = off; off += (bytes + 255) & ~(size_t)255; return o; };
  size_t o_needed = alloc(256*4);
  size_t o_cntp   = alloc((size_t)NSPLIT*NRELS*4);
  size_t o_h0     = alloc((size_t)BG*DIM*4);
  size_t o_X16    = alloc((size_t)MM*DIM*2);
  size_t o_wih16  = alloc((size_t)G3*DIM*2);
  size_t o_whh16  = alloc((size_t)G3*DIM*2);
  size_t o_f0     = alloc((size_t)BG*DIM*4);
  size_t o_f1     = alloc((size_t)BG*DIM*4);
  size_t o_b1v    = alloc((size_t)BG*DIM*4);
  size_t o_b0v    = alloc((size_t)BG*DIM*4);
  size_t o_part   = alloc((size_t)NSPLIT*NRELS*DIM*4);
  size_t o_gi     = alloc((size_t)MM*G3*2);
  (void)ws_size; (void)in_sizes; (void)n_in; (void)out_size;

  int*       needed = (int*)(ws + o_needed);
  int*       cntp   = (int*)(ws + o_cntp);
  float*     h0     = (float*)(ws + o_h0);
  _Float16*  X16    = (_Float16*)(ws + o_X16);
  _Float16*  wih16  = (_Float16*)(ws + o_wih16);
  _Float16*  whh16  = (_Float16*)(ws + o_whh16);
  float*     f0     = (float*)(ws + o_f0);
  float*     f1     = (float*)(ws + o_f1);
  float*     b1v    = (float*)(ws + o_b1v);
  float*     b0v    = (float*)(ws + o_b0v);
  float*     part   = (float*)(ws + o_part);
  _Float16*  gi16   = (_Float16*)(ws + o_gi);

  k_pre   <<<1 + BG + 192, 256, 0, stream>>>(rel, needed, emds, gbias, X16, h0,
                                             wihb, whhb, wih16, whh16);
  k_gemm_gi<<<(MM/64)*(G3/64), 256, 0, stream>>>(X16, wih16, bihb, bhhb, gi16);
  k_mega  <<<NBWD + BG + NSPLIT*4, 512, 0, stream>>>(whh16, gi16, h0, bhhb, b1v, b0v,
                                       emds, gbias, wihf, whhf, bihf, bhhf, f0, f1,
                                       lg_feats, lg_type, needed, part, cntp);
  k_head  <<<BG, 256, 0, stream>>>(f0, f1, b1v, b0v, part, cntp, rel,
                                   W3, b3, W1, b1, W2, b2, out);
}